// Round 5
// baseline (491.313 us; speedup 1.0000x reference)
//
#include <hip/hip_runtime.h>
#include <cmath>

typedef _Float16 f16;
typedef _Float16 f16x2 __attribute__((ext_vector_type(2)));
typedef _Float16 f16x4 __attribute__((ext_vector_type(4)));
typedef _Float16 f16x8 __attribute__((ext_vector_type(8)));
typedef float f32x4 __attribute__((ext_vector_type(4)));

namespace {

constexpr int kB = 8;
constexpr int kL = 680;
constexpr int kH = 24;
constexpr int kD = 64;
constexpr int kC = 1536;          // kH * kD
constexpr int kM = kB * kL;       // 5440
constexpr int kN3 = 3 * kC;       // 4608
constexpr int kNKT = 11;          // ceil(680/64)
constexpr int kNQT = 6;           // ceil(680/128)

// ------------------------------------------------------------- fp32 -> fp16
__global__ void cvt_f32_f16(const float* __restrict__ in,
                            f16* __restrict__ out, int n) {
  int i = (blockIdx.x * blockDim.x + threadIdx.x) * 4;
  if (i >= n) return;  // n is a multiple of 4 for all our arrays
  float4 v = *reinterpret_cast<const float4*>(&in[i]);
  f16x4 o;
  o[0] = (f16)v.x;
  o[1] = (f16)v.y;
  o[2] = (f16)v.z;
  o[3] = (f16)v.w;
  *reinterpret_cast<f16x4*>(&out[i]) = o;
}

// ---------------------------------------------------------------- bias build
__global__ void build_bias_kernel(const float* __restrict__ qb,
                                  const float* __restrict__ vb,
                                  float* __restrict__ bias) {
  int i = blockIdx.x * blockDim.x + threadIdx.x;
  if (i >= kN3) return;
  float v = 0.0f;
  if (i < kC) v = qb[i];
  else if (i >= 2 * kC) v = vb[i - 2 * kC];
  bias[i] = v;
}

// ----------------------------------------------------------- fp16 MFMA GEMM
// C[m][n] = sum_k A[m][k]*Bw[n][k] + bias[n].
// v2: register-prefetch pipeline. Tile k+1's global loads are issued during
// tile k's compute; committed to LDS via ds_write_b128 after the barrier.
// The vmcnt wait thus lands a full iteration after issue — global latency is
// off the critical path (the m97-style global_load_lds structure drained
// vmcnt(0) at every barrier, which at 24 K-iters and ~2 blocks/CU left
// MfmaUtil at 16%).
template <typename OutT>
__global__ __launch_bounds__(256) void gemm_f16(
    const f16* __restrict__ A, const f16* __restrict__ Bw,
    const float* __restrict__ bias, OutT* __restrict__ Cm,
    int M, int N, int K) {
  constexpr int BM = 128, BN = 128, BK = 64;
  __shared__ __align__(16) f16 As[BM * BK];
  __shared__ __align__(16) f16 Bs[BN * BK];
  const int tid = threadIdx.x;
  const int w = tid >> 6;
  const int lane = tid & 63;
  const int lr = lane & 15;
  const int quad = lane >> 4;
  const int wm = (w & 1) * 64;
  const int wn = (w >> 1) * 64;
  const int m0 = blockIdx.y * BM;
  const int n0 = blockIdx.x * BN;

  f32x4 acc[4][4];
#pragma unroll
  for (int i = 0; i < 4; ++i)
#pragma unroll
    for (int j = 0; j < 4; ++j)
#pragma unroll
      for (int c = 0; c < 4; ++c) acc[i][j][c] = 0.0f;

  // chunk = w*4+n covers 64 16B-blocks; linear block L = chunk*64+lane;
  // kb = L>>7 (k-block 0..7), row = L&127.
  int arow[4], akb[4];
#pragma unroll
  for (int n = 0; n < 4; ++n) {
    int Lb = (w * 4 + n) * 64 + lane;
    akb[n] = Lb >> 7;
    arow[n] = Lb & 127;
  }

  f16x8 pa[4], pb[4];
  auto prefetch = [&](int kt) {
#pragma unroll
    for (int n = 0; n < 4; ++n) {
      int rga = m0 + arow[n];
      if (rga > M - 1) rga = M - 1;  // duplicate last row; stores are masked
      pa[n] = *reinterpret_cast<const f16x8*>(&A[(size_t)rga * K + kt +
                                                 akb[n] * 8]);
      int rgb = n0 + arow[n];  // N is a multiple of 128
      pb[n] = *reinterpret_cast<const f16x8*>(&Bw[(size_t)rgb * K + kt +
                                                  akb[n] * 8]);
    }
  };
  prefetch(0);

  for (int kt = 0; kt < K; kt += BK) {
    __syncthreads();  // previous compute done reading LDS
    // commit prefetched tile (vmcnt wait here — loads issued one iter ago)
#pragma unroll
    for (int n = 0; n < 4; ++n) {
      int chunk = w * 4 + n;
      *reinterpret_cast<f16x8*>(&As[chunk * 512 + lane * 8]) = pa[n];
      *reinterpret_cast<f16x8*>(&Bs[chunk * 512 + lane * 8]) = pb[n];
    }
    // issue next tile's loads (latency hidden by this tile's compute)
    prefetch((kt + BK < K) ? kt + BK : kt);
    __syncthreads();  // LDS tiles visible

#pragma unroll
    for (int s = 0; s < 2; ++s) {
      f16x8 af[4], bf[4];
#pragma unroll
      for (int t = 0; t < 4; ++t) {
        af[t] = *reinterpret_cast<const f16x8*>(
            &As[(((s * 4 + quad) << 7) + wm + t * 16 + lr) * 8]);
        bf[t] = *reinterpret_cast<const f16x8*>(
            &Bs[(((s * 4 + quad) << 7) + wn + t * 16 + lr) * 8]);
      }
#pragma unroll
      for (int i = 0; i < 4; ++i)
#pragma unroll
        for (int j = 0; j < 4; ++j)
          acc[i][j] = __builtin_amdgcn_mfma_f32_16x16x32_f16(af[i], bf[j],
                                                             acc[i][j], 0, 0, 0);
    }
  }

  float bv[4];
#pragma unroll
  for (int tn = 0; tn < 4; ++tn) bv[tn] = bias[n0 + wn + tn * 16 + lr];
#pragma unroll
  for (int ti = 0; ti < 4; ++ti) {
#pragma unroll
    for (int tj = 0; tj < 4; ++tj) {
#pragma unroll
      for (int r = 0; r < 4; ++r) {
        int row = m0 + wm + ti * 16 + quad * 4 + r;
        if (row < M) {
          int col = n0 + wn + tj * 16 + lr;
          Cm[(size_t)row * N + col] = (OutT)(acc[ti][tj][r] + bv[tj]);
        }
      }
    }
  }
}

// --------------------------------------------------------------------- RoPE
__global__ void rope_kernel(f16* __restrict__ qkv,
                            const float* __restrict__ pos) {
  int idx = blockIdx.x * blockDim.x + threadIdx.x;
  if (idx >= kM * kH * 32) return;
  int d = idx & 31;
  int rem = idx >> 5;
  int h = rem % kH;
  int bl = rem / kH;
  float p0 = pos[bl * 2 + 0];
  float p1 = pos[bl * 2 + 1];
  float f = exp2f(-(float)(d & 15) * (13.287712379549449f / 16.0f));
  float s0, c0, s1, c1;
  sincosf(p0 * f, &s0, &c0);
  sincosf(p1 * f, &s1, &c1);
  size_t base = (size_t)bl * kN3 + h * kD;
  {
    float t0 = (float)qkv[base + d];
    float t1 = (float)qkv[base + d + 32];
    qkv[base + d] = (f16)(t0 * c0 - t1 * s0);
    qkv[base + d + 32] = (f16)(t1 * c1 + t0 * s1);
  }
  {
    size_t kb = base + kC;
    float t0 = (float)qkv[kb + d];
    float t1 = (float)qkv[kb + d + 32];
    qkv[kb + d] = (f16)(t0 * c0 - t1 * s0);
    qkv[kb + d + 32] = (f16)(t1 * c1 + t0 * s1);
  }
}

// ----------------------------------------------------- MFMA flash attention
// (unchanged from round 4)
__global__ __launch_bounds__(256, 3) void attn_mfma(
    const f16* __restrict__ qkv, f16* __restrict__ attnout) {
  __shared__ __align__(16) f16 Ks[64 * 72];       // [key][d]
  __shared__ __align__(16) f16 Vts[64 * 72];      // [d][key]  (V transposed)
  __shared__ __align__(16) float Pl[4][32 * 68];  // per-wave [qrow][key] f32

  const int tid = threadIdx.x;
  const int w = tid >> 6;
  const int lane = tid & 63;
  const int lr = lane & 15;
  const int qd = lane >> 4;

  const int bid = blockIdx.x;
  const int xcd = bid & 7;
  const int rest = bid >> 3;
  const int qt = rest % kNQT;
  const int g = xcd + 8 * (rest / kNQT);
  const int h = g % kH;
  const int b = g / kH;
  const int q0 = qt * 128;

  f16x8 aq[2][2];
#pragma unroll
  for (int rt = 0; rt < 2; ++rt) {
    int qrow = q0 + w * 32 + rt * 16 + lr;
    if (qrow > kL - 1) qrow = kL - 1;
    const f16* qp = qkv + (size_t)(b * kL + qrow) * kN3 + h * kD;
#pragma unroll
    for (int ks = 0; ks < 2; ++ks)
      aq[rt][ks] =
          *reinterpret_cast<const f16x8*>(qp + ks * 32 + qd * 8);
  }

  const int kkey0 = tid >> 3, kdc = tid & 7;
  const int kkey1 = (tid + 256) >> 3;
  const int vkey0 = (tid & 31) * 2;
  const int vd0 = (tid >> 5) * 8;

  f16x8 kpre0, kpre1, vpre0, vpre1;
  auto prefetch = [&](int kt0) {
    int kg0 = kt0 + kkey0;
    if (kg0 > kL - 1) kg0 = kL - 1;
    kpre0 = *reinterpret_cast<const f16x8*>(
        qkv + (size_t)(b * kL + kg0) * kN3 + kC + h * kD + kdc * 8);
    int kg1 = kt0 + kkey1;
    if (kg1 > kL - 1) kg1 = kL - 1;
    kpre1 = *reinterpret_cast<const f16x8*>(
        qkv + (size_t)(b * kL + kg1) * kN3 + kC + h * kD + kdc * 8);
    int vg0 = kt0 + vkey0;
    if (vg0 > kL - 1) vg0 = kL - 1;
    vpre0 = *reinterpret_cast<const f16x8*>(
        qkv + (size_t)(b * kL + vg0) * kN3 + 2 * kC + h * kD + vd0);
    int vg1 = kt0 + vkey0 + 1;
    if (vg1 > kL - 1) vg1 = kL - 1;
    vpre1 = *reinterpret_cast<const f16x8*>(
        qkv + (size_t)(b * kL + vg1) * kN3 + 2 * kC + h * kD + vd0);
  };
  prefetch(0);

  f32x4 o_acc[2][4];
#pragma unroll
  for (int rt = 0; rt < 2; ++rt)
#pragma unroll
    for (int nt = 0; nt < 4; ++nt)
#pragma unroll
      for (int r = 0; r < 4; ++r) o_acc[rt][nt][r] = 0.0f;
  float lsum[2][4] = {{0.f, 0.f, 0.f, 0.f}, {0.f, 0.f, 0.f, 0.f}};

  for (int it = 0; it < kNKT; ++it) {
    const int kt0 = it * 64;
    __syncthreads();

    *reinterpret_cast<f16x8*>(&Ks[kkey0 * 72 + kdc * 8]) = kpre0;
    *reinterpret_cast<f16x8*>(&Ks[kkey1 * 72 + kdc * 8]) = kpre1;
#pragma unroll
    for (int i = 0; i < 8; ++i) {
      f16x2 pr;
      pr[0] = vpre0[i];
      pr[1] = vpre1[i];
      *reinterpret_cast<f16x2*>(&Vts[(vd0 + i) * 72 + vkey0]) = pr;
    }
    prefetch((it < kNKT - 1) ? (it + 1) * 64 : it * 64);
    __syncthreads();

    f32x4 s_acc[2][4];
#pragma unroll
    for (int rt = 0; rt < 2; ++rt)
#pragma unroll
      for (int t = 0; t < 4; ++t)
#pragma unroll
        for (int r = 0; r < 4; ++r) s_acc[rt][t][r] = 0.0f;
#pragma unroll
    for (int ks = 0; ks < 2; ++ks) {
#pragma unroll
      for (int t = 0; t < 4; ++t) {
        f16x8 bk = *reinterpret_cast<const f16x8*>(
            &Ks[(t * 16 + lr) * 72 + ks * 32 + qd * 8]);
        s_acc[0][t] = __builtin_amdgcn_mfma_f32_16x16x32_f16(
            aq[0][ks], bk, s_acc[0][t], 0, 0, 0);
        s_acc[1][t] = __builtin_amdgcn_mfma_f32_16x16x32_f16(
            aq[1][ks], bk, s_acc[1][t], 0, 0, 0);
      }
    }

#pragma unroll
    for (int rt = 0; rt < 2; ++rt) {
#pragma unroll
      for (int t = 0; t < 4; ++t) {
        const bool valid = (kt0 + t * 16 + lr) < kL;
#pragma unroll
        for (int r = 0; r < 4; ++r) {
          float p = valid ? __expf(s_acc[rt][t][r] * 0.125f) : 0.0f;
          lsum[rt][r] += p;
          Pl[w][(rt * 16 + qd * 4 + r) * 68 + t * 16 + lr] = p;
        }
      }
    }

#pragma unroll
    for (int ks = 0; ks < 2; ++ks) {
      f16x8 ap[2];
#pragma unroll
      for (int rt = 0; rt < 2; ++rt) {
        float4 pa = *reinterpret_cast<const float4*>(
            &Pl[w][(rt * 16 + lr) * 68 + ks * 32 + qd * 8]);
        float4 pb = *reinterpret_cast<const float4*>(
            &Pl[w][(rt * 16 + lr) * 68 + ks * 32 + qd * 8 + 4]);
        ap[rt][0] = (f16)pa.x;
        ap[rt][1] = (f16)pa.y;
        ap[rt][2] = (f16)pa.z;
        ap[rt][3] = (f16)pa.w;
        ap[rt][4] = (f16)pb.x;
        ap[rt][5] = (f16)pb.y;
        ap[rt][6] = (f16)pb.z;
        ap[rt][7] = (f16)pb.w;
      }
#pragma unroll
      for (int nt = 0; nt < 4; ++nt) {
        f16x8 bv = *reinterpret_cast<const f16x8*>(
            &Vts[(nt * 16 + lr) * 72 + ks * 32 + qd * 8]);
        o_acc[0][nt] = __builtin_amdgcn_mfma_f32_16x16x32_f16(
            ap[0], bv, o_acc[0][nt], 0, 0, 0);
        o_acc[1][nt] = __builtin_amdgcn_mfma_f32_16x16x32_f16(
            ap[1], bv, o_acc[1][nt], 0, 0, 0);
      }
    }
  }

#pragma unroll
  for (int rt = 0; rt < 2; ++rt)
#pragma unroll
    for (int r = 0; r < 4; ++r) {
#pragma unroll
      for (int m = 1; m < 16; m <<= 1)
        lsum[rt][r] += __shfl_xor(lsum[rt][r], m, 64);
    }

#pragma unroll
  for (int rt = 0; rt < 2; ++rt) {
#pragma unroll
    for (int nt = 0; nt < 4; ++nt) {
#pragma unroll
      for (int r = 0; r < 4; ++r) {
        int qr = q0 + w * 32 + rt * 16 + qd * 4 + r;
        if (qr < kL) {
          attnout[(size_t)(b * kL + qr) * kC + h * kD + nt * 16 + lr] =
              (f16)(o_acc[rt][nt][r] / lsum[rt][r]);
        }
      }
    }
  }
}

}  // namespace

extern "C" void kernel_launch(void* const* d_in, const int* in_sizes, int n_in,
                              void* d_out, int out_size, void* d_ws,
                              size_t ws_size, hipStream_t stream) {
  const float* x = (const float*)d_in[0];
  const float* pos = (const float*)d_in[1];
  const float* w_qkv = (const float*)d_in[2];
  const float* q_bias = (const float*)d_in[3];
  const float* v_bias = (const float*)d_in[4];
  const float* w_o = (const float*)d_in[5];
  const float* b_o = (const float*)d_in[6];
  float* out = (float*)d_out;

  f16* qkv16 = (f16*)d_ws;                       // kM*kN3
  f16* x16 = qkv16 + (size_t)kM * kN3;           // kM*kC
  f16* wqkv16 = x16 + (size_t)kM * kC;           // kN3*kC
  f16* wo16 = wqkv16 + (size_t)kN3 * kC;         // kC*kC
  f16* ao16 = wo16 + (size_t)kC * kC;            // kM*kC
  float* bias_full = (float*)(ao16 + (size_t)kM * kC);  // kN3 floats

  cvt_f32_f16<<<(kM * kC / 4 + 255) / 256, 256, 0, stream>>>(x, x16, kM * kC);
  cvt_f32_f16<<<(kN3 * kC / 4 + 255) / 256, 256, 0, stream>>>(w_qkv, wqkv16,
                                                              kN3 * kC);
  cvt_f32_f16<<<(kC * kC / 4 + 255) / 256, 256, 0, stream>>>(w_o, wo16,
                                                             kC * kC);
  build_bias_kernel<<<(kN3 + 255) / 256, 256, 0, stream>>>(q_bias, v_bias,
                                                           bias_full);
  gemm_f16<f16><<<dim3(kN3 / 128, (kM + 127) / 128), 256, 0, stream>>>(
      x16, wqkv16, bias_full, qkv16, kM, kN3, kC);
  rope_kernel<<<(kM * kH * 32 + 255) / 256, 256, 0, stream>>>(qkv16, pos);
  attn_mfma<<<dim3(kNQT * kH * kB), 256, 0, stream>>>(qkv16, ao16);
  gemm_f16<float><<<dim3(kC / 128, (kM + 127) / 128), 256, 0, stream>>>(
      ao16, wo16, b_o, out, kM, kC, kC);
}

// Round 6
// 467.897 us; speedup vs baseline: 1.0500x; 1.0500x over previous
//
#include <hip/hip_runtime.h>
#include <cmath>

typedef _Float16 f16;
typedef _Float16 f16x2 __attribute__((ext_vector_type(2)));
typedef _Float16 f16x4 __attribute__((ext_vector_type(4)));
typedef _Float16 f16x8 __attribute__((ext_vector_type(8)));
typedef float f32x4 __attribute__((ext_vector_type(4)));

namespace {

constexpr int kB = 8;
constexpr int kL = 680;
constexpr int kH = 24;
constexpr int kD = 64;
constexpr int kC = 1536;          // kH * kD
constexpr int kM = kB * kL;       // 5440
constexpr int kN3 = 3 * kC;       // 4608
constexpr int kNKT = 11;          // ceil(680/64)
constexpr int kNQT = 6;           // ceil(680/128)

#define ASYNC_CP16(gp, lp)                                          \
  __builtin_amdgcn_global_load_lds(                                 \
      (const __attribute__((address_space(1))) unsigned int*)(gp),  \
      (__attribute__((address_space(3))) unsigned int*)(lp), 16, 0, 0)

// ------------------------------------------------------------- fp32 -> fp16
__global__ void cvt_f32_f16(const float* __restrict__ in,
                            f16* __restrict__ out, int n) {
  int i = (blockIdx.x * blockDim.x + threadIdx.x) * 4;
  if (i >= n) return;  // n is a multiple of 4 for all our arrays
  float4 v = *reinterpret_cast<const float4*>(&in[i]);
  f16x4 o;
  o[0] = (f16)v.x;
  o[1] = (f16)v.y;
  o[2] = (f16)v.z;
  o[3] = (f16)v.w;
  *reinterpret_cast<f16x4*>(&out[i]) = o;
}

// ---------------------------------------------------------------- bias build
__global__ void build_bias_kernel(const float* __restrict__ qb,
                                  const float* __restrict__ vb,
                                  float* __restrict__ bias) {
  int i = blockIdx.x * blockDim.x + threadIdx.x;
  if (i >= kN3) return;
  float v = 0.0f;
  if (i < kC) v = qb[i];
  else if (i >= 2 * kC) v = vb[i - 2 * kC];
  bias[i] = v;
}

// ----------------------------------------------------------- fp16 MFMA GEMM
// C[m][n] = sum_k A[m][k]*Bw[n][k] + bias[n].
// v3: BK=32, double-buffered LDS (4 x 8KB = 32KB, same as v1), ONE barrier
// per K-iteration. global_load_lds for tile i+1 issue right after barrier i;
// the vmcnt(0) drain that consumes them is barrier i+1 — a full compute
// phase later. (v1 issued and drained at the same barrier: zero overlap,
// MfmaUtil 16%. v2's register prefetch cost +24 VGPR and occupancy: 223 us.)
// Wave w stages k-block w (8 halves) for rows lane and lane+64 of A and B.
template <typename OutT>
__global__ __launch_bounds__(256) void gemm_f16(
    const f16* __restrict__ A, const f16* __restrict__ Bw,
    const float* __restrict__ bias, OutT* __restrict__ Cm,
    int M, int N, int K) {
  constexpr int BM = 128, BN = 128, BK = 32;
  __shared__ __align__(16) f16 As[2][BM * BK];
  __shared__ __align__(16) f16 Bs[2][BN * BK];
  const int tid = threadIdx.x;
  const int w = tid >> 6;
  const int lane = tid & 63;
  const int lr = lane & 15;
  const int quad = lane >> 4;
  const int wm = (w & 1) * 64;
  const int wn = (w >> 1) * 64;
  const int m0 = blockIdx.y * BM;
  const int n0 = blockIdx.x * BN;

  f32x4 acc[4][4];
#pragma unroll
  for (int i = 0; i < 4; ++i)
#pragma unroll
    for (int j = 0; j < 4; ++j)
#pragma unroll
      for (int c = 0; c < 4; ++c) acc[i][j][c] = 0.0f;

  // Staging rows for this thread (clamped for the M-tail; stores are masked).
  int ra0 = m0 + lane;
  if (ra0 > M - 1) ra0 = M - 1;
  int ra1 = m0 + 64 + lane;
  if (ra1 > M - 1) ra1 = M - 1;
  const int rb0 = n0 + lane;       // N is a multiple of 128
  const int rb1 = n0 + 64 + lane;

  auto issue = [&](int kt, int buf) {
    // LDS k-major 16B blocks: block index = kb*128 + row, kb = w for this
    // wave. Chunk bases (wave-uniform): w*1024 and w*1024+512 halves.
    ASYNC_CP16(&A[(size_t)ra0 * K + kt + w * 8], &As[buf][w * 1024]);
    ASYNC_CP16(&A[(size_t)ra1 * K + kt + w * 8], &As[buf][w * 1024 + 512]);
    ASYNC_CP16(&Bw[(size_t)rb0 * K + kt + w * 8], &Bs[buf][w * 1024]);
    ASYNC_CP16(&Bw[(size_t)rb1 * K + kt + w * 8], &Bs[buf][w * 1024 + 512]);
  };

  issue(0, 0);
  const int nIter = K / BK;  // 48
  for (int i = 0; i < nIter; ++i) {
    __syncthreads();  // drains vmcnt: tile i resident in buf i&1
    if (i + 1 < nIter) issue((i + 1) * BK, (i + 1) & 1);

    const f16* Asb = As[i & 1];
    const f16* Bsb = Bs[i & 1];
    f16x8 af[4], bf[4];
#pragma unroll
    for (int t = 0; t < 4; ++t) {
      af[t] = *reinterpret_cast<const f16x8*>(
          &Asb[((quad << 7) + wm + t * 16 + lr) * 8]);
      bf[t] = *reinterpret_cast<const f16x8*>(
          &Bsb[((quad << 7) + wn + t * 16 + lr) * 8]);
    }
#pragma unroll
    for (int ti = 0; ti < 4; ++ti)
#pragma unroll
      for (int tj = 0; tj < 4; ++tj)
        acc[ti][tj] = __builtin_amdgcn_mfma_f32_16x16x32_f16(af[ti], bf[tj],
                                                             acc[ti][tj],
                                                             0, 0, 0);
  }

  float bv[4];
#pragma unroll
  for (int tn = 0; tn < 4; ++tn) bv[tn] = bias[n0 + wn + tn * 16 + lr];
#pragma unroll
  for (int ti = 0; ti < 4; ++ti) {
#pragma unroll
    for (int tj = 0; tj < 4; ++tj) {
#pragma unroll
      for (int r = 0; r < 4; ++r) {
        int row = m0 + wm + ti * 16 + quad * 4 + r;
        if (row < M) {
          int col = n0 + wn + tj * 16 + lr;
          Cm[(size_t)row * N + col] = (OutT)(acc[ti][tj][r] + bv[tj]);
        }
      }
    }
  }
}

// --------------------------------------------------------------------- RoPE
__global__ void rope_kernel(f16* __restrict__ qkv,
                            const float* __restrict__ pos) {
  int idx = blockIdx.x * blockDim.x + threadIdx.x;
  if (idx >= kM * kH * 32) return;
  int d = idx & 31;
  int rem = idx >> 5;
  int h = rem % kH;
  int bl = rem / kH;
  float p0 = pos[bl * 2 + 0];
  float p1 = pos[bl * 2 + 1];
  float f = exp2f(-(float)(d & 15) * (13.287712379549449f / 16.0f));
  float s0, c0, s1, c1;
  sincosf(p0 * f, &s0, &c0);
  sincosf(p1 * f, &s1, &c1);
  size_t base = (size_t)bl * kN3 + h * kD;
  {
    float t0 = (float)qkv[base + d];
    float t1 = (float)qkv[base + d + 32];
    qkv[base + d] = (f16)(t0 * c0 - t1 * s0);
    qkv[base + d + 32] = (f16)(t1 * c1 + t0 * s1);
  }
  {
    size_t kb = base + kC;
    float t0 = (float)qkv[kb + d];
    float t1 = (float)qkv[kb + d + 32];
    qkv[kb + d] = (f16)(t0 * c0 - t1 * s0);
    qkv[kb + d + 32] = (f16)(t1 * c1 + t0 * s1);
  }
}

// ----------------------------------------------------- MFMA flash attention
// (unchanged from round 4)
__global__ __launch_bounds__(256, 3) void attn_mfma(
    const f16* __restrict__ qkv, f16* __restrict__ attnout) {
  __shared__ __align__(16) f16 Ks[64 * 72];       // [key][d]
  __shared__ __align__(16) f16 Vts[64 * 72];      // [d][key]  (V transposed)
  __shared__ __align__(16) float Pl[4][32 * 68];  // per-wave [qrow][key] f32

  const int tid = threadIdx.x;
  const int w = tid >> 6;
  const int lane = tid & 63;
  const int lr = lane & 15;
  const int qd = lane >> 4;

  const int bid = blockIdx.x;
  const int xcd = bid & 7;
  const int rest = bid >> 3;
  const int qt = rest % kNQT;
  const int g = xcd + 8 * (rest / kNQT);
  const int h = g % kH;
  const int b = g / kH;
  const int q0 = qt * 128;

  f16x8 aq[2][2];
#pragma unroll
  for (int rt = 0; rt < 2; ++rt) {
    int qrow = q0 + w * 32 + rt * 16 + lr;
    if (qrow > kL - 1) qrow = kL - 1;
    const f16* qp = qkv + (size_t)(b * kL + qrow) * kN3 + h * kD;
#pragma unroll
    for (int ks = 0; ks < 2; ++ks)
      aq[rt][ks] =
          *reinterpret_cast<const f16x8*>(qp + ks * 32 + qd * 8);
  }

  const int kkey0 = tid >> 3, kdc = tid & 7;
  const int kkey1 = (tid + 256) >> 3;
  const int vkey0 = (tid & 31) * 2;
  const int vd0 = (tid >> 5) * 8;

  f16x8 kpre0, kpre1, vpre0, vpre1;
  auto prefetch = [&](int kt0) {
    int kg0 = kt0 + kkey0;
    if (kg0 > kL - 1) kg0 = kL - 1;
    kpre0 = *reinterpret_cast<const f16x8*>(
        qkv + (size_t)(b * kL + kg0) * kN3 + kC + h * kD + kdc * 8);
    int kg1 = kt0 + kkey1;
    if (kg1 > kL - 1) kg1 = kL - 1;
    kpre1 = *reinterpret_cast<const f16x8*>(
        qkv + (size_t)(b * kL + kg1) * kN3 + kC + h * kD + kdc * 8);
    int vg0 = kt0 + vkey0;
    if (vg0 > kL - 1) vg0 = kL - 1;
    vpre0 = *reinterpret_cast<const f16x8*>(
        qkv + (size_t)(b * kL + vg0) * kN3 + 2 * kC + h * kD + vd0);
    int vg1 = kt0 + vkey0 + 1;
    if (vg1 > kL - 1) vg1 = kL - 1;
    vpre1 = *reinterpret_cast<const f16x8*>(
        qkv + (size_t)(b * kL + vg1) * kN3 + 2 * kC + h * kD + vd0);
  };
  prefetch(0);

  f32x4 o_acc[2][4];
#pragma unroll
  for (int rt = 0; rt < 2; ++rt)
#pragma unroll
    for (int nt = 0; nt < 4; ++nt)
#pragma unroll
      for (int r = 0; r < 4; ++r) o_acc[rt][nt][r] = 0.0f;
  float lsum[2][4] = {{0.f, 0.f, 0.f, 0.f}, {0.f, 0.f, 0.f, 0.f}};

  for (int it = 0; it < kNKT; ++it) {
    const int kt0 = it * 64;
    __syncthreads();

    *reinterpret_cast<f16x8*>(&Ks[kkey0 * 72 + kdc * 8]) = kpre0;
    *reinterpret_cast<f16x8*>(&Ks[kkey1 * 72 + kdc * 8]) = kpre1;
#pragma unroll
    for (int i = 0; i < 8; ++i) {
      f16x2 pr;
      pr[0] = vpre0[i];
      pr[1] = vpre1[i];
      *reinterpret_cast<f16x2*>(&Vts[(vd0 + i) * 72 + vkey0]) = pr;
    }
    prefetch((it < kNKT - 1) ? (it + 1) * 64 : it * 64);
    __syncthreads();

    f32x4 s_acc[2][4];
#pragma unroll
    for (int rt = 0; rt < 2; ++rt)
#pragma unroll
      for (int t = 0; t < 4; ++t)
#pragma unroll
        for (int r = 0; r < 4; ++r) s_acc[rt][t][r] = 0.0f;
#pragma unroll
    for (int ks = 0; ks < 2; ++ks) {
#pragma unroll
      for (int t = 0; t < 4; ++t) {
        f16x8 bk = *reinterpret_cast<const f16x8*>(
            &Ks[(t * 16 + lr) * 72 + ks * 32 + qd * 8]);
        s_acc[0][t] = __builtin_amdgcn_mfma_f32_16x16x32_f16(
            aq[0][ks], bk, s_acc[0][t], 0, 0, 0);
        s_acc[1][t] = __builtin_amdgcn_mfma_f32_16x16x32_f16(
            aq[1][ks], bk, s_acc[1][t], 0, 0, 0);
      }
    }

#pragma unroll
    for (int rt = 0; rt < 2; ++rt) {
#pragma unroll
      for (int t = 0; t < 4; ++t) {
        const bool valid = (kt0 + t * 16 + lr) < kL;
#pragma unroll
        for (int r = 0; r < 4; ++r) {
          float p = valid ? __expf(s_acc[rt][t][r] * 0.125f) : 0.0f;
          lsum[rt][r] += p;
          Pl[w][(rt * 16 + qd * 4 + r) * 68 + t * 16 + lr] = p;
        }
      }
    }

#pragma unroll
    for (int ks = 0; ks < 2; ++ks) {
      f16x8 ap[2];
#pragma unroll
      for (int rt = 0; rt < 2; ++rt) {
        float4 pa = *reinterpret_cast<const float4*>(
            &Pl[w][(rt * 16 + lr) * 68 + ks * 32 + qd * 8]);
        float4 pb = *reinterpret_cast<const float4*>(
            &Pl[w][(rt * 16 + lr) * 68 + ks * 32 + qd * 8 + 4]);
        ap[rt][0] = (f16)pa.x;
        ap[rt][1] = (f16)pa.y;
        ap[rt][2] = (f16)pa.z;
        ap[rt][3] = (f16)pa.w;
        ap[rt][4] = (f16)pb.x;
        ap[rt][5] = (f16)pb.y;
        ap[rt][6] = (f16)pb.z;
        ap[rt][7] = (f16)pb.w;
      }
#pragma unroll
      for (int nt = 0; nt < 4; ++nt) {
        f16x8 bv = *reinterpret_cast<const f16x8*>(
            &Vts[(nt * 16 + lr) * 72 + ks * 32 + qd * 8]);
        o_acc[0][nt] = __builtin_amdgcn_mfma_f32_16x16x32_f16(
            ap[0], bv, o_acc[0][nt], 0, 0, 0);
        o_acc[1][nt] = __builtin_amdgcn_mfma_f32_16x16x32_f16(
            ap[1], bv, o_acc[1][nt], 0, 0, 0);
      }
    }
  }

#pragma unroll
  for (int rt = 0; rt < 2; ++rt)
#pragma unroll
    for (int r = 0; r < 4; ++r) {
#pragma unroll
      for (int m = 1; m < 16; m <<= 1)
        lsum[rt][r] += __shfl_xor(lsum[rt][r], m, 64);
    }

#pragma unroll
  for (int rt = 0; rt < 2; ++rt) {
#pragma unroll
    for (int nt = 0; nt < 4; ++nt) {
#pragma unroll
      for (int r = 0; r < 4; ++r) {
        int qr = q0 + w * 32 + rt * 16 + qd * 4 + r;
        if (qr < kL) {
          attnout[(size_t)(b * kL + qr) * kC + h * kD + nt * 16 + lr] =
              (f16)(o_acc[rt][nt][r] / lsum[rt][r]);
        }
      }
    }
  }
}

}  // namespace

extern "C" void kernel_launch(void* const* d_in, const int* in_sizes, int n_in,
                              void* d_out, int out_size, void* d_ws,
                              size_t ws_size, hipStream_t stream) {
  const float* x = (const float*)d_in[0];
  const float* pos = (const float*)d_in[1];
  const float* w_qkv = (const float*)d_in[2];
  const float* q_bias = (const float*)d_in[3];
  const float* v_bias = (const float*)d_in[4];
  const float* w_o = (const float*)d_in[5];
  const float* b_o = (const float*)d_in[6];
  float* out = (float*)d_out;

  f16* qkv16 = (f16*)d_ws;                       // kM*kN3
  f16* x16 = qkv16 + (size_t)kM * kN3;           // kM*kC
  f16* wqkv16 = x16 + (size_t)kM * kC;           // kN3*kC
  f16* wo16 = wqkv16 + (size_t)kN3 * kC;         // kC*kC
  f16* ao16 = wo16 + (size_t)kC * kC;            // kM*kC
  float* bias_full = (float*)(ao16 + (size_t)kM * kC);  // kN3 floats

  cvt_f32_f16<<<(kM * kC / 4 + 255) / 256, 256, 0, stream>>>(x, x16, kM * kC);
  cvt_f32_f16<<<(kN3 * kC / 4 + 255) / 256, 256, 0, stream>>>(w_qkv, wqkv16,
                                                              kN3 * kC);
  cvt_f32_f16<<<(kC * kC / 4 + 255) / 256, 256, 0, stream>>>(w_o, wo16,
                                                             kC * kC);
  build_bias_kernel<<<(kN3 + 255) / 256, 256, 0, stream>>>(q_bias, v_bias,
                                                           bias_full);
  gemm_f16<f16><<<dim3(kN3 / 128, (kM + 127) / 128), 256, 0, stream>>>(
      x16, wqkv16, bias_full, qkv16, kM, kN3, kC);
  rope_kernel<<<(kM * kH * 32 + 255) / 256, 256, 0, stream>>>(qkv16, pos);
  attn_mfma<<<dim3(kNQT * kH * kB), 256, 0, stream>>>(qkv16, ao16);
  gemm_f16<float><<<dim3(kC / 128, (kM + 127) / 128), 256, 0, stream>>>(
      ao16, wo16, b_o, out, kM, kC, kC);
}

// Round 7
// 439.367 us; speedup vs baseline: 1.1182x; 1.0649x over previous
//
#include <hip/hip_runtime.h>
#include <cmath>

typedef _Float16 f16;
typedef _Float16 f16x2 __attribute__((ext_vector_type(2)));
typedef _Float16 f16x4 __attribute__((ext_vector_type(4)));
typedef _Float16 f16x8 __attribute__((ext_vector_type(8)));
typedef float f32x4 __attribute__((ext_vector_type(4)));

namespace {

constexpr int kB = 8;
constexpr int kL = 680;
constexpr int kH = 24;
constexpr int kD = 64;
constexpr int kC = 1536;          // kH * kD
constexpr int kM = kB * kL;       // 5440
constexpr int kN3 = 3 * kC;       // 4608
constexpr int kNKT = 11;          // ceil(680/64)
constexpr int kNQT = 6;           // ceil(680/128)

#define ASYNC_CP16(gp, lp)                                          \
  __builtin_amdgcn_global_load_lds(                                 \
      (const __attribute__((address_space(1))) unsigned int*)(gp),  \
      (__attribute__((address_space(3))) unsigned int*)(lp), 16, 0, 0)

// ------------------------------------------------------------- fp32 -> fp16
__global__ void cvt_f32_f16(const float* __restrict__ in,
                            f16* __restrict__ out, int n) {
  int i = (blockIdx.x * blockDim.x + threadIdx.x) * 4;
  if (i >= n) return;  // n is a multiple of 4 for all our arrays
  float4 v = *reinterpret_cast<const float4*>(&in[i]);
  f16x4 o;
  o[0] = (f16)v.x;
  o[1] = (f16)v.y;
  o[2] = (f16)v.z;
  o[3] = (f16)v.w;
  *reinterpret_cast<f16x4*>(&out[i]) = o;
}

// ---------------------------------------------------------------- bias build
__global__ void build_bias_kernel(const float* __restrict__ qb,
                                  const float* __restrict__ vb,
                                  float* __restrict__ bias) {
  int i = blockIdx.x * blockDim.x + threadIdx.x;
  if (i >= kN3) return;
  float v = 0.0f;
  if (i < kC) v = qb[i];
  else if (i >= 2 * kC) v = vb[i - 2 * kC];
  bias[i] = v;
}

// ----------------------------------------------------------- fp16 MFMA GEMM
// C[m][n] = sum_k A[m][k]*Bw[n][k] + bias[n].
// v4: BM=128, BN=256, BK=64, round-3's 2-barrier global_load_lds structure.
// Rationale: latency exposure scales with per-CU serial block-iterations
// (was 1548 blks x 24 it / 256 CU = 145 windows; now 774 x 24 / 256 = 72),
// and compute per window doubles (32 MFMA/wave). v2 (reg prefetch) and v3
// (BK=32 dbuf) both failed to hide latency; this amortizes it instead.
// Wave w owns a 64x128 patch: wm=(w&1)*64, wn=(w>>1)*128, acc 4x8 tiles.
template <typename OutT>
__global__ __launch_bounds__(256, 2) void gemm_f16(
    const f16* __restrict__ A, const f16* __restrict__ Bw,
    const float* __restrict__ bias, OutT* __restrict__ Cm,
    int M, int N, int K) {
  constexpr int BM = 128, BN = 256, BK = 64;
  __shared__ __align__(16) f16 As[BM * BK];   // 16 KB, k-major 16B blocks
  __shared__ __align__(16) f16 Bs[BN * BK];   // 32 KB
  const int tid = threadIdx.x;
  const int w = tid >> 6;
  const int lane = tid & 63;
  const int lr = lane & 15;
  const int quad = lane >> 4;
  const int wm = (w & 1) * 64;
  const int wn = (w >> 1) * 128;
  const int m0 = blockIdx.y * BM;
  const int n0 = blockIdx.x * BN;

  f32x4 acc[4][8];
#pragma unroll
  for (int i = 0; i < 4; ++i)
#pragma unroll
    for (int j = 0; j < 8; ++j)
#pragma unroll
      for (int c = 0; c < 4; ++c) acc[i][j][c] = 0.0f;

  // A staging: 1024 16B-blocks; chunk = w*4+n covers 64; La = chunk*64+lane;
  // kb = La>>7, row = La&127.
  int arow[4], akb[4];
#pragma unroll
  for (int n = 0; n < 4; ++n) {
    int La = (w * 4 + n) * 64 + lane;
    akb[n] = La >> 7;
    arow[n] = La & 127;
  }
  // B staging: 2048 16B-blocks; chunkB = w*8+n; Lb = chunkB*64+lane;
  // kb = Lb>>8, row = Lb&255.
  int brow[8], bkb[8];
#pragma unroll
  for (int n = 0; n < 8; ++n) {
    int Lb = (w * 8 + n) * 64 + lane;
    bkb[n] = Lb >> 8;
    brow[n] = Lb & 255;
  }

  for (int kt = 0; kt < K; kt += BK) {
#pragma unroll
    for (int n = 0; n < 4; ++n) {
      int chunk = w * 4 + n;
      int rga = m0 + arow[n];
      if (rga > M - 1) rga = M - 1;  // duplicate last row; stores are masked
      ASYNC_CP16(&A[(size_t)rga * K + kt + akb[n] * 8], &As[chunk * 512]);
    }
#pragma unroll
    for (int n = 0; n < 8; ++n) {
      int chunk = w * 8 + n;
      int rgb = n0 + brow[n];  // N is a multiple of 256
      ASYNC_CP16(&Bw[(size_t)rgb * K + kt + bkb[n] * 8], &Bs[chunk * 512]);
    }
    __syncthreads();  // drains vmcnt -> LDS tiles complete

#pragma unroll
    for (int s = 0; s < 2; ++s) {
      f16x8 af[4], bf[8];
#pragma unroll
      for (int t = 0; t < 4; ++t)
        af[t] = *reinterpret_cast<const f16x8*>(
            &As[(((s * 4 + quad) << 7) + wm + t * 16 + lr) * 8]);
#pragma unroll
      for (int t = 0; t < 8; ++t)
        bf[t] = *reinterpret_cast<const f16x8*>(
            &Bs[(((s * 4 + quad) << 8) + wn + t * 16 + lr) * 8]);
#pragma unroll
      for (int i = 0; i < 4; ++i)
#pragma unroll
        for (int j = 0; j < 8; ++j)
          acc[i][j] = __builtin_amdgcn_mfma_f32_16x16x32_f16(af[i], bf[j],
                                                             acc[i][j], 0, 0, 0);
    }
    __syncthreads();  // all waves done reading LDS before next stage
  }

  // Epilogue: C/D layout col = lane&15 (n), row = quad*4+reg (m).
  float bv[8];
#pragma unroll
  for (int tn = 0; tn < 8; ++tn) bv[tn] = bias[n0 + wn + tn * 16 + lr];
#pragma unroll
  for (int ti = 0; ti < 4; ++ti) {
#pragma unroll
    for (int tj = 0; tj < 8; ++tj) {
#pragma unroll
      for (int r = 0; r < 4; ++r) {
        int row = m0 + wm + ti * 16 + quad * 4 + r;
        if (row < M) {
          int col = n0 + wn + tj * 16 + lr;
          Cm[(size_t)row * N + col] = (OutT)(acc[ti][tj][r] + bv[tj]);
        }
      }
    }
  }
}

// --------------------------------------------------------------------- RoPE
__global__ void rope_kernel(f16* __restrict__ qkv,
                            const float* __restrict__ pos) {
  int idx = blockIdx.x * blockDim.x + threadIdx.x;
  if (idx >= kM * kH * 32) return;
  int d = idx & 31;
  int rem = idx >> 5;
  int h = rem % kH;
  int bl = rem / kH;
  float p0 = pos[bl * 2 + 0];
  float p1 = pos[bl * 2 + 1];
  float f = exp2f(-(float)(d & 15) * (13.287712379549449f / 16.0f));
  float s0, c0, s1, c1;
  sincosf(p0 * f, &s0, &c0);
  sincosf(p1 * f, &s1, &c1);
  size_t base = (size_t)bl * kN3 + h * kD;
  {
    float t0 = (float)qkv[base + d];
    float t1 = (float)qkv[base + d + 32];
    qkv[base + d] = (f16)(t0 * c0 - t1 * s0);
    qkv[base + d + 32] = (f16)(t1 * c1 + t0 * s1);
  }
  {
    size_t kb = base + kC;
    float t0 = (float)qkv[kb + d];
    float t1 = (float)qkv[kb + d + 32];
    qkv[kb + d] = (f16)(t0 * c0 - t1 * s0);
    qkv[kb + d + 32] = (f16)(t1 * c1 + t0 * s1);
  }
}

// ----------------------------------------------------- MFMA flash attention
// (unchanged from round 4)
__global__ __launch_bounds__(256, 3) void attn_mfma(
    const f16* __restrict__ qkv, f16* __restrict__ attnout) {
  __shared__ __align__(16) f16 Ks[64 * 72];       // [key][d]
  __shared__ __align__(16) f16 Vts[64 * 72];      // [d][key]  (V transposed)
  __shared__ __align__(16) float Pl[4][32 * 68];  // per-wave [qrow][key] f32

  const int tid = threadIdx.x;
  const int w = tid >> 6;
  const int lane = tid & 63;
  const int lr = lane & 15;
  const int qd = lane >> 4;

  const int bid = blockIdx.x;
  const int xcd = bid & 7;
  const int rest = bid >> 3;
  const int qt = rest % kNQT;
  const int g = xcd + 8 * (rest / kNQT);
  const int h = g % kH;
  const int b = g / kH;
  const int q0 = qt * 128;

  f16x8 aq[2][2];
#pragma unroll
  for (int rt = 0; rt < 2; ++rt) {
    int qrow = q0 + w * 32 + rt * 16 + lr;
    if (qrow > kL - 1) qrow = kL - 1;
    const f16* qp = qkv + (size_t)(b * kL + qrow) * kN3 + h * kD;
#pragma unroll
    for (int ks = 0; ks < 2; ++ks)
      aq[rt][ks] =
          *reinterpret_cast<const f16x8*>(qp + ks * 32 + qd * 8);
  }

  const int kkey0 = tid >> 3, kdc = tid & 7;
  const int kkey1 = (tid + 256) >> 3;
  const int vkey0 = (tid & 31) * 2;
  const int vd0 = (tid >> 5) * 8;

  f16x8 kpre0, kpre1, vpre0, vpre1;
  auto prefetch = [&](int kt0) {
    int kg0 = kt0 + kkey0;
    if (kg0 > kL - 1) kg0 = kL - 1;
    kpre0 = *reinterpret_cast<const f16x8*>(
        qkv + (size_t)(b * kL + kg0) * kN3 + kC + h * kD + kdc * 8);
    int kg1 = kt0 + kkey1;
    if (kg1 > kL - 1) kg1 = kL - 1;
    kpre1 = *reinterpret_cast<const f16x8*>(
        qkv + (size_t)(b * kL + kg1) * kN3 + kC + h * kD + kdc * 8);
    int vg0 = kt0 + vkey0;
    if (vg0 > kL - 1) vg0 = kL - 1;
    vpre0 = *reinterpret_cast<const f16x8*>(
        qkv + (size_t)(b * kL + vg0) * kN3 + 2 * kC + h * kD + vd0);
    int vg1 = kt0 + vkey0 + 1;
    if (vg1 > kL - 1) vg1 = kL - 1;
    vpre1 = *reinterpret_cast<const f16x8*>(
        qkv + (size_t)(b * kL + vg1) * kN3 + 2 * kC + h * kD + vd0);
  };
  prefetch(0);

  f32x4 o_acc[2][4];
#pragma unroll
  for (int rt = 0; rt < 2; ++rt)
#pragma unroll
    for (int nt = 0; nt < 4; ++nt)
#pragma unroll
      for (int r = 0; r < 4; ++r) o_acc[rt][nt][r] = 0.0f;
  float lsum[2][4] = {{0.f, 0.f, 0.f, 0.f}, {0.f, 0.f, 0.f, 0.f}};

  for (int it = 0; it < kNKT; ++it) {
    const int kt0 = it * 64;
    __syncthreads();

    *reinterpret_cast<f16x8*>(&Ks[kkey0 * 72 + kdc * 8]) = kpre0;
    *reinterpret_cast<f16x8*>(&Ks[kkey1 * 72 + kdc * 8]) = kpre1;
#pragma unroll
    for (int i = 0; i < 8; ++i) {
      f16x2 pr;
      pr[0] = vpre0[i];
      pr[1] = vpre1[i];
      *reinterpret_cast<f16x2*>(&Vts[(vd0 + i) * 72 + vkey0]) = pr;
    }
    prefetch((it < kNKT - 1) ? (it + 1) * 64 : it * 64);
    __syncthreads();

    f32x4 s_acc[2][4];
#pragma unroll
    for (int rt = 0; rt < 2; ++rt)
#pragma unroll
      for (int t = 0; t < 4; ++t)
#pragma unroll
        for (int r = 0; r < 4; ++r) s_acc[rt][t][r] = 0.0f;
#pragma unroll
    for (int ks = 0; ks < 2; ++ks) {
#pragma unroll
      for (int t = 0; t < 4; ++t) {
        f16x8 bk = *reinterpret_cast<const f16x8*>(
            &Ks[(t * 16 + lr) * 72 + ks * 32 + qd * 8]);
        s_acc[0][t] = __builtin_amdgcn_mfma_f32_16x16x32_f16(
            aq[0][ks], bk, s_acc[0][t], 0, 0, 0);
        s_acc[1][t] = __builtin_amdgcn_mfma_f32_16x16x32_f16(
            aq[1][ks], bk, s_acc[1][t], 0, 0, 0);
      }
    }

#pragma unroll
    for (int rt = 0; rt < 2; ++rt) {
#pragma unroll
      for (int t = 0; t < 4; ++t) {
        const bool valid = (kt0 + t * 16 + lr) < kL;
#pragma unroll
        for (int r = 0; r < 4; ++r) {
          float p = valid ? __expf(s_acc[rt][t][r] * 0.125f) : 0.0f;
          lsum[rt][r] += p;
          Pl[w][(rt * 16 + qd * 4 + r) * 68 + t * 16 + lr] = p;
        }
      }
    }

#pragma unroll
    for (int ks = 0; ks < 2; ++ks) {
      f16x8 ap[2];
#pragma unroll
      for (int rt = 0; rt < 2; ++rt) {
        float4 pa = *reinterpret_cast<const float4*>(
            &Pl[w][(rt * 16 + lr) * 68 + ks * 32 + qd * 8]);
        float4 pb = *reinterpret_cast<const float4*>(
            &Pl[w][(rt * 16 + lr) * 68 + ks * 32 + qd * 8 + 4]);
        ap[rt][0] = (f16)pa.x;
        ap[rt][1] = (f16)pa.y;
        ap[rt][2] = (f16)pa.z;
        ap[rt][3] = (f16)pa.w;
        ap[rt][4] = (f16)pb.x;
        ap[rt][5] = (f16)pb.y;
        ap[rt][6] = (f16)pb.z;
        ap[rt][7] = (f16)pb.w;
      }
#pragma unroll
      for (int nt = 0; nt < 4; ++nt) {
        f16x8 bv = *reinterpret_cast<const f16x8*>(
            &Vts[(nt * 16 + lr) * 72 + ks * 32 + qd * 8]);
        o_acc[0][nt] = __builtin_amdgcn_mfma_f32_16x16x32_f16(
            ap[0], bv, o_acc[0][nt], 0, 0, 0);
        o_acc[1][nt] = __builtin_amdgcn_mfma_f32_16x16x32_f16(
            ap[1], bv, o_acc[1][nt], 0, 0, 0);
      }
    }
  }

#pragma unroll
  for (int rt = 0; rt < 2; ++rt)
#pragma unroll
    for (int r = 0; r < 4; ++r) {
#pragma unroll
      for (int m = 1; m < 16; m <<= 1)
        lsum[rt][r] += __shfl_xor(lsum[rt][r], m, 64);
    }

#pragma unroll
  for (int rt = 0; rt < 2; ++rt) {
#pragma unroll
    for (int nt = 0; nt < 4; ++nt) {
#pragma unroll
      for (int r = 0; r < 4; ++r) {
        int qr = q0 + w * 32 + rt * 16 + qd * 4 + r;
        if (qr < kL) {
          attnout[(size_t)(b * kL + qr) * kC + h * kD + nt * 16 + lr] =
              (f16)(o_acc[rt][nt][r] / lsum[rt][r]);
        }
      }
    }
  }
}

}  // namespace

extern "C" void kernel_launch(void* const* d_in, const int* in_sizes, int n_in,
                              void* d_out, int out_size, void* d_ws,
                              size_t ws_size, hipStream_t stream) {
  const float* x = (const float*)d_in[0];
  const float* pos = (const float*)d_in[1];
  const float* w_qkv = (const float*)d_in[2];
  const float* q_bias = (const float*)d_in[3];
  const float* v_bias = (const float*)d_in[4];
  const float* w_o = (const float*)d_in[5];
  const float* b_o = (const float*)d_in[6];
  float* out = (float*)d_out;

  f16* qkv16 = (f16*)d_ws;                       // kM*kN3
  f16* x16 = qkv16 + (size_t)kM * kN3;           // kM*kC
  f16* wqkv16 = x16 + (size_t)kM * kC;           // kN3*kC
  f16* wo16 = wqkv16 + (size_t)kN3 * kC;         // kC*kC
  f16* ao16 = wo16 + (size_t)kC * kC;            // kM*kC
  float* bias_full = (float*)(ao16 + (size_t)kM * kC);  // kN3 floats

  cvt_f32_f16<<<(kM * kC / 4 + 255) / 256, 256, 0, stream>>>(x, x16, kM * kC);
  cvt_f32_f16<<<(kN3 * kC / 4 + 255) / 256, 256, 0, stream>>>(w_qkv, wqkv16,
                                                              kN3 * kC);
  cvt_f32_f16<<<(kC * kC / 4 + 255) / 256, 256, 0, stream>>>(w_o, wo16,
                                                             kC * kC);
  build_bias_kernel<<<(kN3 + 255) / 256, 256, 0, stream>>>(q_bias, v_bias,
                                                           bias_full);
  gemm_f16<f16><<<dim3(kN3 / 256, (kM + 127) / 128), 256, 0, stream>>>(
      x16, wqkv16, bias_full, qkv16, kM, kN3, kC);
  rope_kernel<<<(kM * kH * 32 + 255) / 256, 256, 0, stream>>>(qkv16, pos);
  attn_mfma<<<dim3(kNQT * kH * kB), 256, 0, stream>>>(qkv16, ao16);
  gemm_f16<float><<<dim3(kC / 256, (kM + 127) / 128), 256, 0, stream>>>(
      ao16, wo16, b_o, out, kM, kC, kC);
}